// Round 4
// baseline (828.557 us; speedup 1.0000x reference)
//
#include <hip/hip_runtime.h>
#include <math.h>

#define B_ 8
#define C_ 128
#define O3_ 384
#define H_ 128
#define W_ 128
#define L_ 16384
#define NS_ 64
#define MAXP_ 2304

typedef float f32x4 __attribute__((ext_vector_type(4)));
typedef short bf16x8 __attribute__((ext_vector_type(8)));

static __device__ __forceinline__ ushort f2bf(float f) {
    uint u = __float_as_uint(f);
    u += 0x7fffu + ((u >> 16) & 1u);
    return (ushort)(u >> 16);
}
static __device__ __forceinline__ float bf2f(ushort h) {
    return __uint_as_float(((uint)h) << 16);
}

// ---------------------------------------------------------------------------
// Transpose+split: x [b][128c][L] fp32 -> xThi/xTlo [b][L][128c] bf16 planes
// ---------------------------------------------------------------------------
__global__ __launch_bounds__(256) void transp_k(const float* __restrict__ x,
    short* __restrict__ xhi, short* __restrict__ xlo)
{
    __shared__ float t[128][33];
    const int b = blockIdx.y;
    const int l0 = blockIdx.x * 32;
    const int tid = threadIdx.x;
    {
        const int c = tid >> 1, half = tid & 1;
        const float* src = x + ((size_t)b * C_ + c) * L_ + l0 + half * 16;
#pragma unroll
        for (int u = 0; u < 4; u++) {
            float4 v = *reinterpret_cast<const float4*>(src + u * 4);
            t[c][half * 16 + u * 4 + 0] = v.x;
            t[c][half * 16 + u * 4 + 1] = v.y;
            t[c][half * 16 + u * 4 + 2] = v.z;
            t[c][half * 16 + u * 4 + 3] = v.w;
        }
    }
    __syncthreads();
    {
        const int l = tid >> 3, strip = tid & 7;
        uint hi[8], lo[8];
#pragma unroll
        for (int i = 0; i < 8; i++) {
            float a0 = t[strip * 16 + 2 * i][l], a1 = t[strip * 16 + 2 * i + 1][l];
            ushort h0 = f2bf(a0), h1 = f2bf(a1);
            ushort g0 = f2bf(a0 - bf2f(h0)), g1 = f2bf(a1 - bf2f(h1));
            hi[i] = (uint)h0 | ((uint)h1 << 16);
            lo[i] = (uint)g0 | ((uint)g1 << 16);
        }
        size_t ob = ((size_t)b * L_ + l0 + l) * C_ + strip * 16;
        uint4* ph = reinterpret_cast<uint4*>(xhi + ob);
        uint4* pl = reinterpret_cast<uint4*>(xlo + ob);
        ph[0] = *reinterpret_cast<uint4*>(&hi[0]);
        ph[1] = *reinterpret_cast<uint4*>(&hi[4]);
        pl[0] = *reinterpret_cast<uint4*>(&lo[0]);
        pl[1] = *reinterpret_cast<uint4*>(&lo[4]);
    }
}

// ---------------------------------------------------------------------------
// NT MFMA GEMM (bf16x3). A pre-split hi/lo planes [b][L][KD].
// W fp32 [o][KD], converted per tile (cheap).
// MODE 1: y = gelu(acc+bias) * (A-reconstruct at yi)  -> split store [l][o]
// MODE 2: y = acc+bias                                 -> split store [l][o]
// MODE 3: y = acc+bias+E0                              -> split store [l][o]
// MODE 4: plain, fp32 transposed store [o][l]
// ---------------------------------------------------------------------------
template<int KD, int OT, int MODE>
__global__ __launch_bounds__(256) void mgemm_k(
    const float* __restrict__ Wf, const float* __restrict__ bias,
    const short* __restrict__ Ahi, const short* __restrict__ Alo,
    const float* __restrict__ E0,
    float* __restrict__ Yf, short* __restrict__ Yhi, short* __restrict__ Ylo)
{
    constexpr int NR = OT / 32;
    __shared__ short sAh[128][40];
    __shared__ short sAl[128][40];
    __shared__ short sBh[OT][40];
    __shared__ short sBl[OT][40];
    const int tid = threadIdx.x;
    const int lane = tid & 63;
    const int wid = tid >> 6;
    const int wr = wid >> 1, wc = wid & 1;
    const int oB = blockIdx.x * OT;
    const int lB = blockIdx.y * 128;
    const int ON = gridDim.x * OT;
    const int b = blockIdx.z;
    const int ln15 = lane & 15, lg = lane >> 4;

    f32x4 acc[4][NR];
#pragma unroll
    for (int m = 0; m < 4; m++)
#pragma unroll
        for (int n = 0; n < NR; n++)
#pragma unroll
            for (int r = 0; r < 4; r++) acc[m][n][r] = 0.f;

    for (int kc = 0; kc < KD; kc += 32) {
        // A: pure copies of pre-split planes (128 l x 32 c)
        for (int p = tid; p < 512; p += 256) {
            int l = p >> 2, c8 = (p & 3) * 8;
            size_t g = ((size_t)b * L_ + lB + l) * KD + kc + c8;
            *reinterpret_cast<bf16x8*>(&sAh[l][c8]) = *reinterpret_cast<const bf16x8*>(&Ahi[g]);
            *reinterpret_cast<bf16x8*>(&sAl[l][c8]) = *reinterpret_cast<const bf16x8*>(&Alo[g]);
        }
        // B: convert fp32 W tile (OT o x 32 c)
        for (int p = tid; p < OT * 8; p += 256) {
            int o = p >> 3, c4 = (p & 7) * 4;
            float4 v = *reinterpret_cast<const float4*>(&Wf[(size_t)(oB + o) * KD + kc + c4]);
            ushort h0 = f2bf(v.x), h1 = f2bf(v.y), h2 = f2bf(v.z), h3 = f2bf(v.w);
            ushort g0 = f2bf(v.x - bf2f(h0)), g1 = f2bf(v.y - bf2f(h1));
            ushort g2 = f2bf(v.z - bf2f(h2)), g3 = f2bf(v.w - bf2f(h3));
            uint2 uh = {(uint)h0 | ((uint)h1 << 16), (uint)h2 | ((uint)h3 << 16)};
            uint2 ul = {(uint)g0 | ((uint)g1 << 16), (uint)g2 | ((uint)g3 << 16)};
            *reinterpret_cast<uint2*>(&sBh[o][c4]) = uh;
            *reinterpret_cast<uint2*>(&sBl[o][c4]) = ul;
        }
        __syncthreads();
        bf16x8 Ah[4], Al[4];
#pragma unroll
        for (int m = 0; m < 4; m++) {
            int row = wr * 64 + m * 16 + ln15;
            Ah[m] = *reinterpret_cast<const bf16x8*>(&sAh[row][lg * 8]);
            Al[m] = *reinterpret_cast<const bf16x8*>(&sAl[row][lg * 8]);
        }
#pragma unroll
        for (int n = 0; n < NR; n++) {
            int brow = wc * (OT / 2) + n * 16 + ln15;
            bf16x8 Bh = *reinterpret_cast<const bf16x8*>(&sBh[brow][lg * 8]);
            bf16x8 Bl = *reinterpret_cast<const bf16x8*>(&sBl[brow][lg * 8]);
#pragma unroll
            for (int m = 0; m < 4; m++) {
                acc[m][n] = __builtin_amdgcn_mfma_f32_16x16x32_bf16(Ah[m], Bh, acc[m][n], 0, 0, 0);
                acc[m][n] = __builtin_amdgcn_mfma_f32_16x16x32_bf16(Ah[m], Bl, acc[m][n], 0, 0, 0);
                acc[m][n] = __builtin_amdgcn_mfma_f32_16x16x32_bf16(Al[m], Bh, acc[m][n], 0, 0, 0);
            }
        }
        __syncthreads();
    }

#pragma unroll
    for (int m = 0; m < 4; m++) {
        const int lg4 = lB + wr * 64 + m * 16 + lg * 4;
#pragma unroll
        for (int n = 0; n < NR; n++) {
            const int o = oB + wc * (OT / 2) + n * 16 + ln15;
            if constexpr (MODE == 4) {
                float4 r4 = {acc[m][n][0], acc[m][n][1], acc[m][n][2], acc[m][n][3]};
                *reinterpret_cast<float4*>(&Yf[((size_t)b * ON + o) * L_ + lg4]) = r4;
            } else {
                float bv = bias[o];
#pragma unroll
                for (int r = 0; r < 4; r++) {
                    size_t yi = ((size_t)b * L_ + lg4 + r) * ON + o;
                    float a = acc[m][n][r] + bv;
                    if constexpr (MODE == 1) {
                        float sxy = bf2f((ushort)Ahi[yi]) + bf2f((ushort)Alo[yi]);
                        a = 0.5f * a * (1.f + erff(a * 0.70710678118654752f)) * sxy;
                    }
                    if constexpr (MODE == 3) a += E0[yi];
                    ushort h = f2bf(a);
                    ushort g = f2bf(a - bf2f(h));
                    Yhi[yi] = (short)h;
                    Ylo[yi] = (short)g;
                }
            }
        }
    }
}

// ---------------------------------------------------------------------------
// Depthwise 3x3 SAME conv, register-rolling, fused q/k sum & sumsq reduction
// One block per (ch, b). 256 thr = 32 x-strips(4px) x 8 y-bands(16 rows)
// ---------------------------------------------------------------------------
__global__ __launch_bounds__(256) void dwconv_k(const float* __restrict__ in,
    const float* __restrict__ wdw, float* __restrict__ outp,
    float* __restrict__ sumq, float* __restrict__ sumk,
    float* __restrict__ ssq, float* __restrict__ ssk)
{
    const int ch = blockIdx.x, b = blockIdx.y;
    const int tid = threadIdx.x;
    const int tx = tid & 31, band = tid >> 5;
    const int x0 = tx * 4;
    const int y0 = band * 16;
    const size_t base = ((size_t)b * O3_ + ch) * L_;
    const float* wp = wdw + ch * 9;
    float w0 = wp[0], w1 = wp[1], w2 = wp[2], w3 = wp[3], w4 = wp[4],
          w5 = wp[5], w6 = wp[6], w7 = wp[7], w8 = wp[8];

    float s1 = 0.f, s2 = 0.f;
    float b0[6], b1[6], b2[6];

    auto loadrow = [&](int gy, float* r) {
        if ((unsigned)gy < (unsigned)H_) {
            const float* rp = in + base + (size_t)gy * W_;
            float4 m = *reinterpret_cast<const float4*>(rp + x0);
            r[0] = (x0 > 0) ? rp[x0 - 1] : 0.f;
            r[1] = m.x; r[2] = m.y; r[3] = m.z; r[4] = m.w;
            r[5] = (x0 < W_ - 4) ? rp[x0 + 4] : 0.f;
        } else {
            r[0] = r[1] = r[2] = r[3] = r[4] = r[5] = 0.f;
        }
    };
    auto conv3 = [&](const float* ra, const float* rb, const float* rc, int yy) {
        float o0 = ra[0]*w0 + ra[1]*w1 + ra[2]*w2 + rb[0]*w3 + rb[1]*w4 + rb[2]*w5 + rc[0]*w6 + rc[1]*w7 + rc[2]*w8;
        float o1 = ra[1]*w0 + ra[2]*w1 + ra[3]*w2 + rb[1]*w3 + rb[2]*w4 + rb[3]*w5 + rc[1]*w6 + rc[2]*w7 + rc[3]*w8;
        float o2 = ra[2]*w0 + ra[3]*w1 + ra[4]*w2 + rb[2]*w3 + rb[3]*w4 + rb[4]*w5 + rc[2]*w6 + rc[3]*w7 + rc[4]*w8;
        float o3 = ra[3]*w0 + ra[4]*w1 + ra[5]*w2 + rb[3]*w3 + rb[4]*w4 + rb[5]*w5 + rc[3]*w6 + rc[4]*w7 + rc[5]*w8;
        float4 o4 = {o0, o1, o2, o3};
        *reinterpret_cast<float4*>(&outp[base + (size_t)(y0 + yy) * W_ + x0]) = o4;
        s1 += (o0 + o1) + (o2 + o3);
        s2 += o0*o0 + o1*o1 + o2*o2 + o3*o3;
    };

    loadrow(y0 - 1, b0);
    loadrow(y0,     b1);
#pragma unroll
    for (int y3 = 0; y3 < 15; y3 += 3) {
        loadrow(y0 + y3 + 1, b2); conv3(b0, b1, b2, y3);
        loadrow(y0 + y3 + 2, b0); conv3(b1, b2, b0, y3 + 1);
        loadrow(y0 + y3 + 3, b1); conv3(b2, b0, b1, y3 + 2);
    }
    loadrow(y0 + 16, b2); conv3(b0, b1, b2, 15);

    __shared__ float r1[256], r2[256];
    if (ch < 256) {
        r1[tid] = s1; r2[tid] = s2;
        __syncthreads();
        for (int st = 128; st > 0; st >>= 1) {
            if (tid < st) { r1[tid] += r1[tid + st]; r2[tid] += r2[tid + st]; }
            __syncthreads();
        }
        if (tid == 0) {
            if (ch < 128) { sumq[b * 128 + ch] = r1[0]; ssq[b * 128 + ch] = r2[0]; }
            else          { sumk[b * 128 + ch - 128] = r1[0]; ssk[b * 128 + ch - 128] = r2[0]; }
        }
    }
}

// combine: channel means (double) -> stable rank; rq,rk; gm
__global__ void combine_k(const float* __restrict__ sumq, const float* __restrict__ sumk,
    const float* __restrict__ ssq, const float* __restrict__ ssk,
    int* __restrict__ idxp, float* __restrict__ rqc, float* __restrict__ rkc,
    float* __restrict__ gm)
{
    const int t = threadIdx.x; // 128
    __shared__ double cms[128];
    double s = 0.0;
    for (int b = 0; b < B_; b++) s += (double)sumq[b * 128 + t];
    cms[t] = s;
    float rqv[B_], rkv[B_];
    for (int b = 0; b < B_; b++) {
        rqv[b] = 1.f / fmaxf(sqrtf(ssq[b * 128 + t]), 1e-12f);
        rkv[b] = 1.f / fmaxf(sqrtf(ssk[b * 128 + t]), 1e-12f);
        rqc[b * 128 + t] = rqv[b];
        rkc[b * 128 + t] = rkv[b];
    }
    __syncthreads();
    const double mv = cms[t];
    int r = 0;
    for (int j = 0; j < 128; j++) {
        double o = cms[j];
        if (o > mv || (o == mv && j < t)) r++;
    }
    idxp[r] = t;
    for (int b = 0; b < B_; b++)
        gm[b * 128 + r] = (rqv[b] * sumq[b * 128 + t] + rkv[b] * sumk[b * 128 + t]) * (1.0f / L_);
}

// ---------------------------------------------------------------------------
// Partial raw scores (merged groups): S[c][d] = sum_l q[c,l]*k[d,l]
// ---------------------------------------------------------------------------
template<int G>
__device__ __forceinline__ void score_body(const float* __restrict__ dw,
    const int* __restrict__ idxp, int start, int gi, float* __restrict__ spart,
    float* sQ, float* sK, int* sc)
{
    constexpr int TS = G / 16;
    const int split = blockIdx.x, b = blockIdx.y;
    const int tid = threadIdx.x, tx = tid & 15, ty = tid >> 4;
    if (tid < G) sc[tid] = idxp[start + tid];
    __syncthreads();

    float acc[TS][TS];
#pragma unroll
    for (int i = 0; i < TS; i++)
#pragma unroll
        for (int j = 0; j < TS; j++) acc[i][j] = 0.f;

    const int l0 = split * (L_ / NS_);
    constexpr int LPT = (G * 64) / 256;
    for (int chk = 0; chk < L_ / NS_; chk += 64) {
#pragma unroll
        for (int i = 0; i < LPT; i++) {
            int id = tid + i * 256;
            int row = id >> 6, lc = id & 63;
            size_t base = ((size_t)b * O3_ + sc[row]) * L_ + l0 + chk + lc;
            sQ[row * 66 + lc] = dw[base];
            sK[row * 66 + lc] = dw[base + (size_t)128 * L_];
        }
        __syncthreads();
#pragma unroll
        for (int kk = 0; kk < 64; kk++) {
            float qv[TS], kv[TS];
#pragma unroll
            for (int j = 0; j < TS; j++) {
                qv[j] = sQ[(ty * TS + j) * 66 + kk];
                kv[j] = sK[(tx * TS + j) * 66 + kk];
            }
#pragma unroll
            for (int i = 0; i < TS; i++)
#pragma unroll
                for (int j = 0; j < TS; j++)
                    acc[i][j] = fmaf(qv[i], kv[j], acc[i][j]);
        }
        __syncthreads();
    }
    float* op = spart + (((size_t)(b * 4 + gi)) * NS_ + split) * MAXP_;
#pragma unroll
    for (int i = 0; i < TS; i++)
#pragma unroll
        for (int j = 0; j < TS; j++)
            op[(ty * TS + i) * G + tx * TS + j] = acc[i][j];
}

__global__ __launch_bounds__(256) void score_k(const float* __restrict__ dw,
    const int* __restrict__ idxp, float* __restrict__ spart)
{
    __shared__ float sQ[48 * 66];
    __shared__ float sK[48 * 66];
    __shared__ int sc[48];
    switch (blockIdx.z) {
        case 0: score_body<16>(dw, idxp, 0, 0, spart, sQ, sK, sc); break;
        case 1: score_body<32>(dw, idxp, 16, 1, spart, sQ, sK, sc); break;
        case 2: score_body<32>(dw, idxp, 48, 2, spart, sQ, sK, sc); break;
        default: score_body<48>(dw, idxp, 80, 3, spart, sQ, sK, sc); break;
    }
}

// reduce partials, scale by rq*rk*temp, softmax rows -> attn
__global__ __launch_bounds__(256) void softmax_k(const float* __restrict__ spart,
    const float* __restrict__ rqc, const float* __restrict__ rkc, const int* __restrict__ idxp,
    const float* __restrict__ temp, float* __restrict__ attn)
{
    const int gi = blockIdx.x, b = blockIdx.y;
    const int g = (gi == 0) ? 16 : (gi == 3 ? 48 : 32);
    const int start = (gi == 0) ? 0 : (gi == 1 ? 16 : (gi == 2 ? 48 : 80));
    __shared__ float S[MAXP_];
    __shared__ int sidx[48];
    if (threadIdx.x < g) sidx[threadIdx.x] = idxp[start + threadIdx.x];
    __syncthreads();
    const float tv = temp[gi];
    for (int p = threadIdx.x; p < g * g; p += 256) {
        float s = 0.f;
        const float* sp = spart + ((size_t)(b * 4 + gi)) * NS_ * MAXP_ + p;
        for (int k = 0; k < NS_; k++) s += sp[(size_t)k * MAXP_];
        int cc = p / g, dd = p - cc * g;
        S[p] = s * rqc[b * 128 + sidx[cc]] * rkc[b * 128 + sidx[dd]] * tv;
    }
    __syncthreads();
    const int wv = threadIdx.x >> 6, lane = threadIdx.x & 63;
    for (int r = wv; r < g; r += 4) {
        float val = (lane < g) ? S[r * g + lane] : -1e30f;
        float mx = val;
        for (int m = 32; m > 0; m >>= 1) mx = fmaxf(mx, __shfl_xor(mx, m));
        float e = (lane < g) ? expf(val - mx) : 0.f;
        float sum = e;
        for (int m = 32; m > 0; m >>= 1) sum += __shfl_xor(sum, m);
        if (lane < g) attn[((size_t)(b * 4 + gi)) * MAXP_ + r * g + lane] = e / sum;
    }
}

// ---------------------------------------------------------------------------
// attn @ v (merged groups): outallT fp32 [b][l][c]; sxy split hi/lo planes
// ---------------------------------------------------------------------------
template<int G>
__device__ __forceinline__ void av2_body(const float* __restrict__ dw,
    const int* __restrict__ idxp, const float* __restrict__ rqc, const float* __restrict__ rkc,
    const float* __restrict__ attn, int start, int gi,
    float* __restrict__ outallT, short* __restrict__ sxyhi, short* __restrict__ sxylo,
    float* sA, float* sV, float* sQ2, float* sK2, int* cv, float* rqs, float* rks)
{
    constexpr int C4 = G / 4;
    constexpr int GP = G + 1;
    const int b = blockIdx.y;
    const int lB = blockIdx.x * 64;
    const int tid = threadIdx.x;
    if (tid < G) {
        int c0 = idxp[start + tid];
        cv[tid] = c0;
        rqs[tid] = rqc[b * 128 + c0];
        rks[tid] = rkc[b * 128 + c0];
    }
    for (int p = tid; p < G * G; p += 256) {
        int cc = p / G, dd = p - cc * G;
        sA[cc * GP + dd] = attn[((size_t)(b * 4 + gi)) * MAXP_ + p];
    }
    __syncthreads();
    for (int idx = tid; idx < 64 * G; idx += 256) {
        int l = idx & 63, d = idx >> 6;
        size_t base = ((size_t)b * O3_ + cv[d]) * L_ + lB + l;
        sQ2[l * GP + d] = dw[base];
        sK2[l * GP + d] = dw[base + (size_t)128 * L_];
        sV[l * GP + d]  = dw[base + (size_t)256 * L_];
    }
    __syncthreads();
    const int strip = tid & 3, l = tid >> 2;
    float acc[C4];
#pragma unroll
    for (int j = 0; j < C4; j++) acc[j] = 0.f;
    for (int d = 0; d < G; d++) {
        float vd = sV[l * GP + d];
#pragma unroll
        for (int j = 0; j < C4; j++)
            acc[j] = fmaf(sA[(strip * C4 + j) * GP + d], vd, acc[j]);
    }
    const size_t ob = ((size_t)b * L_ + lB + l) * C_ + start + strip * C4;
    float sv[C4];
#pragma unroll
    for (int j = 0; j < C4; j++) {
        int c = strip * C4 + j;
        sv[j] = acc[j] + rqs[c] * sQ2[l * GP + c] + rks[c] * sK2[l * GP + c];
    }
#pragma unroll
    for (int j = 0; j < C4; j += 4) {
        float4 o4 = {acc[j], acc[j + 1], acc[j + 2], acc[j + 3]};
        *reinterpret_cast<float4*>(&outallT[ob + j]) = o4;
    }
#pragma unroll
    for (int j = 0; j < C4; j += 2) {
        ushort h0 = f2bf(sv[j]), h1 = f2bf(sv[j + 1]);
        ushort g0 = f2bf(sv[j] - bf2f(h0)), g1 = f2bf(sv[j + 1] - bf2f(h1));
        *reinterpret_cast<uint*>(&sxyhi[ob + j]) = (uint)h0 | ((uint)h1 << 16);
        *reinterpret_cast<uint*>(&sxylo[ob + j]) = (uint)g0 | ((uint)g1 << 16);
    }
}

__global__ __launch_bounds__(256) void av2_k(const float* __restrict__ dw,
    const int* __restrict__ idxp, const float* __restrict__ rqc, const float* __restrict__ rkc,
    const float* __restrict__ attn, float* __restrict__ outallT,
    short* __restrict__ sxyhi, short* __restrict__ sxylo)
{
    __shared__ float sA[48 * 49];
    __shared__ float sV[64 * 49], sQ2[64 * 49], sK2[64 * 49];
    __shared__ int cv[48];
    __shared__ float rqs[48], rks[48];
    switch (blockIdx.z) {
        case 0: av2_body<16>(dw, idxp, rqc, rkc, attn, 0, 0, outallT, sxyhi, sxylo, sA, sV, sQ2, sK2, cv, rqs, rks); break;
        case 1: av2_body<32>(dw, idxp, rqc, rkc, attn, 16, 1, outallT, sxyhi, sxylo, sA, sV, sQ2, sK2, cv, rqs, rks); break;
        case 2: av2_body<32>(dw, idxp, rqc, rkc, attn, 48, 2, outallT, sxyhi, sxylo, sA, sV, sQ2, sK2, cv, rqs, rks); break;
        default: av2_body<48>(dw, idxp, rqc, rkc, attn, 80, 3, outallT, sxyhi, sxylo, sA, sV, sQ2, sK2, cv, rqs, rks); break;
    }
}

// qv_cache = 0.9 * mean of tiled group means, broadcast over spatial
__global__ __launch_bounds__(256) void qvc_k(const float* __restrict__ gm, float* __restrict__ outq)
{
    const int cpos = blockIdx.x, b = blockIdx.y;
    const float* g = gm + b * 128;
    float v = g[cpos & 15] + g[16 + (cpos & 31)] + g[48 + (cpos & 31)];
    if (cpos < 96) v += g[80 + (cpos % 48)];
    v *= 0.225f; // 0.9 * (sum/4)
    float4 vv = {v, v, v, v};
    float4* op = reinterpret_cast<float4*>(outq + ((size_t)b * C_ + cpos) * L_);
    for (int i = threadIdx.x; i < L_ / 4; i += 256) op[i] = vv;
}

// ---------------------------------------------------------------------------
extern "C" void kernel_launch(void* const* d_in, const int* in_sizes, int n_in,
                              void* d_out, int out_size, void* d_ws, size_t ws_size,
                              hipStream_t stream)
{
    const float* x     = (const float*)d_in[0];
    const float* temp  = (const float*)d_in[1];
    const float* wqkv  = (const float*)d_in[2];
    const float* wdw   = (const float*)d_in[3];
    const float* wproj = (const float*)d_in[4];
    const float* wgate = (const float*)d_in[5];
    const float* bgate = (const float*)d_in[6];
    const float* wdown = (const float*)d_in[7];
    const float* bdown = (const float*)d_in[8];
    const float* wup   = (const float*)d_in[9];
    const float* bup   = (const float*)d_in[10];
    float* out = (float*)d_out;
    float* ws  = (float*)d_ws;

    // --- ws layout ---
    float* qkvCL = ws;                          // [b][384][L] fp32  [0, 50331648)
    float* dwCL  = ws + 50331648ull;            // [b][384][L] fp32  [50331648, 100663296)
    // xT planes live inside dwCL region until dwconv overwrites (xT dead by then)
    short* xThi  = (short*)(ws + 50331648ull);
    short* xTlo  = xThi + 16777216ull;
    // qkvCL region reused after dwconv:
    float* outallT = ws;                        // fp32 [b][L][128]   [0, 16777216)
    short* sxyhi   = (short*)(ws + 16777216ull);
    short* sxylo   = sxyhi + 16777216ull;       // floats [16777216, 33554432)
    short* gatedhi = (short*)(ws + 33554432ull);
    short* gatedlo = gatedhi + 16777216ull;     // floats [33554432, 50331648)
    short* mod1hi  = (short*)(ws + 16777216ull);// reuse over dead sxy
    short* mod1lo  = mod1hi + 8388608ull;       // floats [16777216, 25165824)
    short* out2hi  = (short*)(ws + 33554432ull);// reuse over dead gated
    short* out2lo  = out2hi + 16777216ull;

    // --- d_out layout (first half scratch until proj; second half qv_cache) ---
    float* spart = out;                         // [0, 4718592)
    float* attn  = out + 4718592ull;            // 73728
    float* sumq  = out + 4800000ull;
    float* sumk  = out + 4801024ull;
    float* ssq   = out + 4802048ull;
    float* ssk   = out + 4803072ull;
    float* rqc   = out + 4804096ull;
    float* rkc   = out + 4805120ull;
    float* gm    = out + 4806144ull;
    int*   idxp  = (int*)(out + 4807168ull);

    // 1. transpose+split x -> xThi/xTlo [b][l][c]
    transp_k<<<dim3(512, 8), 256, 0, stream>>>(x, xThi, xTlo);
    // 2. qkv GEMM -> qkvCL fp32 [b][384][l] (o-major grid for A-tile L2 reuse)
    mgemm_k<128, 128, 4><<<dim3(3, 128, 8), 256, 0, stream>>>(
        wqkv, nullptr, xThi, xTlo, nullptr, qkvCL, nullptr, nullptr);
    // 3. depthwise 3x3 + fused q/k sums (overwrites xT region)
    dwconv_k<<<dim3(384, 8), 256, 0, stream>>>(qkvCL, wdw, dwCL, sumq, sumk, ssq, ssk);
    // 4. combine: rank + norms + gm
    combine_k<<<1, 128, 0, stream>>>(sumq, sumk, ssq, ssk, idxp, rqc, rkc, gm);
    // 5. attention scores (all groups, one launch)
    score_k<<<dim3(NS_, 8, 4), 256, 0, stream>>>(dwCL, idxp, spart);
    // 6. reduce + softmax
    softmax_k<<<dim3(4, 8), 256, 0, stream>>>(spart, rqc, rkc, idxp, temp, attn);
    // 7. attn @ v (all groups, one launch) -> outallT fp32 + sxy hi/lo planes
    av2_k<<<dim3(256, 8, 4), 256, 0, stream>>>(dwCL, idxp, rqc, rkc, attn, outallT, sxyhi, sxylo);
    // 8. gate GEMM (+gelu * sxy) -> gated hi/lo
    mgemm_k<128, 128, 1><<<dim3(1, 128, 8), 256, 0, stream>>>(
        wgate, bgate, sxyhi, sxylo, nullptr, nullptr, gatedhi, gatedlo);
    // 9. qv_cache (reads gm; writes d_out second half; before proj)
    qvc_k<<<dim3(128, 8), 256, 0, stream>>>(gm, out + 16777216ull);
    // 10. down GEMM -> mod1 hi/lo
    mgemm_k<128, 64, 2><<<dim3(1, 128, 8), 256, 0, stream>>>(
        wdown, bdown, gatedhi, gatedlo, nullptr, nullptr, mod1hi, mod1lo);
    // 11. up GEMM + residual -> out2 hi/lo
    mgemm_k<64, 128, 3><<<dim3(1, 128, 8), 256, 0, stream>>>(
        wup, bup, mod1hi, mod1lo, outallT, nullptr, out2hi, out2lo);
    // 12. proj GEMM -> final output fp32 [b][128][l] (overwrites scratch)
    mgemm_k<128, 128, 4><<<dim3(1, 128, 8), 256, 0, stream>>>(
        wproj, nullptr, out2hi, out2lo, nullptr, out, nullptr, nullptr);
}

// Round 5
// 828.492 us; speedup vs baseline: 1.0001x; 1.0001x over previous
//
#include <hip/hip_runtime.h>
#include <math.h>

#define B_ 8
#define C_ 128
#define O3_ 384
#define H_ 128
#define W_ 128
#define L_ 16384
#define NS_ 64
#define MAXP_ 2304

typedef float f32x4 __attribute__((ext_vector_type(4)));
typedef short bf16x8 __attribute__((ext_vector_type(8)));

static __device__ __forceinline__ ushort f2bf(float f) {
    uint u = __float_as_uint(f);
    u += 0x7fffu + ((u >> 16) & 1u);
    return (ushort)(u >> 16);
}
static __device__ __forceinline__ float bf2f(ushort h) {
    return __uint_as_float(((uint)h) << 16);
}

// ---------------------------------------------------------------------------
// Transpose+split: x [b][128c][L] fp32 -> xThi/xTlo [b][L][128c] bf16 planes
// ---------------------------------------------------------------------------
__global__ __launch_bounds__(256) void transp_k(const float* __restrict__ x,
    short* __restrict__ xhi, short* __restrict__ xlo)
{
    __shared__ float t[128][33];
    const int b = blockIdx.y;
    const int l0 = blockIdx.x * 32;
    const int tid = threadIdx.x;
    {
        const int c = tid >> 1, half = tid & 1;
        const float* src = x + ((size_t)b * C_ + c) * L_ + l0 + half * 16;
#pragma unroll
        for (int u = 0; u < 4; u++) {
            float4 v = *reinterpret_cast<const float4*>(src + u * 4);
            t[c][half * 16 + u * 4 + 0] = v.x;
            t[c][half * 16 + u * 4 + 1] = v.y;
            t[c][half * 16 + u * 4 + 2] = v.z;
            t[c][half * 16 + u * 4 + 3] = v.w;
        }
    }
    __syncthreads();
    {
        const int l = tid >> 3, strip = tid & 7;
        uint hi[8], lo[8];
#pragma unroll
        for (int i = 0; i < 8; i++) {
            float a0 = t[strip * 16 + 2 * i][l], a1 = t[strip * 16 + 2 * i + 1][l];
            ushort h0 = f2bf(a0), h1 = f2bf(a1);
            ushort g0 = f2bf(a0 - bf2f(h0)), g1 = f2bf(a1 - bf2f(h1));
            hi[i] = (uint)h0 | ((uint)h1 << 16);
            lo[i] = (uint)g0 | ((uint)g1 << 16);
        }
        size_t ob = ((size_t)b * L_ + l0 + l) * C_ + strip * 16;
        uint4* ph = reinterpret_cast<uint4*>(xhi + ob);
        uint4* pl = reinterpret_cast<uint4*>(xlo + ob);
        ph[0] = *reinterpret_cast<uint4*>(&hi[0]);
        ph[1] = *reinterpret_cast<uint4*>(&hi[4]);
        pl[0] = *reinterpret_cast<uint4*>(&lo[0]);
        pl[1] = *reinterpret_cast<uint4*>(&lo[4]);
    }
}

// ---------------------------------------------------------------------------
// NT MFMA GEMM (bf16x3). A pre-split hi/lo planes [b][L][KD].
// MODE 1: y = gelu(acc+bias) * (A-reconstruct at yi)  -> split store [l][o]
// MODE 2: y = acc+bias                                 -> split store [l][o]
// MODE 3: y = acc+bias+E0                              -> split store [l][o]
// MODE 4: plain, fp32 transposed store [o][l]
// ---------------------------------------------------------------------------
template<int KD, int OT, int MODE>
__global__ __launch_bounds__(256) void mgemm_k(
    const float* __restrict__ Wf, const float* __restrict__ bias,
    const short* __restrict__ Ahi, const short* __restrict__ Alo,
    const float* __restrict__ E0,
    float* __restrict__ Yf, short* __restrict__ Yhi, short* __restrict__ Ylo)
{
    constexpr int NR = OT / 32;
    __shared__ short sAh[128][40];
    __shared__ short sAl[128][40];
    __shared__ short sBh[OT][40];
    __shared__ short sBl[OT][40];
    const int tid = threadIdx.x;
    const int lane = tid & 63;
    const int wid = tid >> 6;
    const int wr = wid >> 1, wc = wid & 1;
    const int oB = blockIdx.x * OT;
    const int lB = blockIdx.y * 128;
    const int ON = gridDim.x * OT;
    const int b = blockIdx.z;
    const int ln15 = lane & 15, lg = lane >> 4;

    f32x4 acc[4][NR];
#pragma unroll
    for (int m = 0; m < 4; m++)
#pragma unroll
        for (int n = 0; n < NR; n++)
#pragma unroll
            for (int r = 0; r < 4; r++) acc[m][n][r] = 0.f;

    for (int kc = 0; kc < KD; kc += 32) {
        for (int p = tid; p < 512; p += 256) {
            int l = p >> 2, c8 = (p & 3) * 8;
            size_t g = ((size_t)b * L_ + lB + l) * KD + kc + c8;
            *reinterpret_cast<bf16x8*>(&sAh[l][c8]) = *reinterpret_cast<const bf16x8*>(&Ahi[g]);
            *reinterpret_cast<bf16x8*>(&sAl[l][c8]) = *reinterpret_cast<const bf16x8*>(&Alo[g]);
        }
        for (int p = tid; p < OT * 8; p += 256) {
            int o = p >> 3, c4 = (p & 7) * 4;
            float4 v = *reinterpret_cast<const float4*>(&Wf[(size_t)(oB + o) * KD + kc + c4]);
            ushort h0 = f2bf(v.x), h1 = f2bf(v.y), h2 = f2bf(v.z), h3 = f2bf(v.w);
            ushort g0 = f2bf(v.x - bf2f(h0)), g1 = f2bf(v.y - bf2f(h1));
            ushort g2 = f2bf(v.z - bf2f(h2)), g3 = f2bf(v.w - bf2f(h3));
            uint2 uh = {(uint)h0 | ((uint)h1 << 16), (uint)h2 | ((uint)h3 << 16)};
            uint2 ul = {(uint)g0 | ((uint)g1 << 16), (uint)g2 | ((uint)g3 << 16)};
            *reinterpret_cast<uint2*>(&sBh[o][c4]) = uh;
            *reinterpret_cast<uint2*>(&sBl[o][c4]) = ul;
        }
        __syncthreads();
        bf16x8 Ah[4], Al[4];
#pragma unroll
        for (int m = 0; m < 4; m++) {
            int row = wr * 64 + m * 16 + ln15;
            Ah[m] = *reinterpret_cast<const bf16x8*>(&sAh[row][lg * 8]);
            Al[m] = *reinterpret_cast<const bf16x8*>(&sAl[row][lg * 8]);
        }
#pragma unroll
        for (int n = 0; n < NR; n++) {
            int brow = wc * (OT / 2) + n * 16 + ln15;
            bf16x8 Bh = *reinterpret_cast<const bf16x8*>(&sBh[brow][lg * 8]);
            bf16x8 Bl = *reinterpret_cast<const bf16x8*>(&sBl[brow][lg * 8]);
#pragma unroll
            for (int m = 0; m < 4; m++) {
                acc[m][n] = __builtin_amdgcn_mfma_f32_16x16x32_bf16(Ah[m], Bh, acc[m][n], 0, 0, 0);
                acc[m][n] = __builtin_amdgcn_mfma_f32_16x16x32_bf16(Ah[m], Bl, acc[m][n], 0, 0, 0);
                acc[m][n] = __builtin_amdgcn_mfma_f32_16x16x32_bf16(Al[m], Bh, acc[m][n], 0, 0, 0);
            }
        }
        __syncthreads();
    }

#pragma unroll
    for (int m = 0; m < 4; m++) {
        const int lg4 = lB + wr * 64 + m * 16 + lg * 4;
#pragma unroll
        for (int n = 0; n < NR; n++) {
            const int o = oB + wc * (OT / 2) + n * 16 + ln15;
            if constexpr (MODE == 4) {
                float4 r4 = {acc[m][n][0], acc[m][n][1], acc[m][n][2], acc[m][n][3]};
                *reinterpret_cast<float4*>(&Yf[((size_t)b * ON + o) * L_ + lg4]) = r4;
            } else {
                float bv = bias[o];
#pragma unroll
                for (int r = 0; r < 4; r++) {
                    size_t yi = ((size_t)b * L_ + lg4 + r) * ON + o;
                    float a = acc[m][n][r] + bv;
                    if constexpr (MODE == 1) {
                        float sxy = bf2f((ushort)Ahi[yi]) + bf2f((ushort)Alo[yi]);
                        a = 0.5f * a * (1.f + erff(a * 0.70710678118654752f)) * sxy;
                    }
                    if constexpr (MODE == 3) a += E0[yi];
                    ushort h = f2bf(a);
                    ushort g = f2bf(a - bf2f(h));
                    Yhi[yi] = (short)h;
                    Ylo[yi] = (short)g;
                }
            }
        }
    }
}

// ---------------------------------------------------------------------------
// Depthwise 3x3 SAME conv, register-rolling, fused q/k sum & sumsq reduction
// ---------------------------------------------------------------------------
__global__ __launch_bounds__(256) void dwconv_k(const float* __restrict__ in,
    const float* __restrict__ wdw, float* __restrict__ outp,
    float* __restrict__ sumq, float* __restrict__ sumk,
    float* __restrict__ ssq, float* __restrict__ ssk)
{
    const int ch = blockIdx.x, b = blockIdx.y;
    const int tid = threadIdx.x;
    const int tx = tid & 31, band = tid >> 5;
    const int x0 = tx * 4;
    const int y0 = band * 16;
    const size_t base = ((size_t)b * O3_ + ch) * L_;
    const float* wp = wdw + ch * 9;
    float w0 = wp[0], w1 = wp[1], w2 = wp[2], w3 = wp[3], w4 = wp[4],
          w5 = wp[5], w6 = wp[6], w7 = wp[7], w8 = wp[8];

    float s1 = 0.f, s2 = 0.f;
    float b0[6], b1[6], b2[6];

    auto loadrow = [&](int gy, float* r) {
        if ((unsigned)gy < (unsigned)H_) {
            const float* rp = in + base + (size_t)gy * W_;
            float4 m = *reinterpret_cast<const float4*>(rp + x0);
            r[0] = (x0 > 0) ? rp[x0 - 1] : 0.f;
            r[1] = m.x; r[2] = m.y; r[3] = m.z; r[4] = m.w;
            r[5] = (x0 < W_ - 4) ? rp[x0 + 4] : 0.f;
        } else {
            r[0] = r[1] = r[2] = r[3] = r[4] = r[5] = 0.f;
        }
    };
    auto conv3 = [&](const float* ra, const float* rb, const float* rc, int yy) {
        float o0 = ra[0]*w0 + ra[1]*w1 + ra[2]*w2 + rb[0]*w3 + rb[1]*w4 + rb[2]*w5 + rc[0]*w6 + rc[1]*w7 + rc[2]*w8;
        float o1 = ra[1]*w0 + ra[2]*w1 + ra[3]*w2 + rb[1]*w3 + rb[2]*w4 + rb[3]*w5 + rc[1]*w6 + rc[2]*w7 + rc[3]*w8;
        float o2 = ra[2]*w0 + ra[3]*w1 + ra[4]*w2 + rb[2]*w3 + rb[3]*w4 + rb[4]*w5 + rc[2]*w6 + rc[3]*w7 + rc[4]*w8;
        float o3 = ra[3]*w0 + ra[4]*w1 + ra[5]*w2 + rb[3]*w3 + rb[4]*w4 + rb[5]*w5 + rc[3]*w6 + rc[4]*w7 + rc[5]*w8;
        float4 o4 = {o0, o1, o2, o3};
        *reinterpret_cast<float4*>(&outp[base + (size_t)(y0 + yy) * W_ + x0]) = o4;
        s1 += (o0 + o1) + (o2 + o3);
        s2 += o0*o0 + o1*o1 + o2*o2 + o3*o3;
    };

    loadrow(y0 - 1, b0);
    loadrow(y0,     b1);
#pragma unroll
    for (int y3 = 0; y3 < 15; y3 += 3) {
        loadrow(y0 + y3 + 1, b2); conv3(b0, b1, b2, y3);
        loadrow(y0 + y3 + 2, b0); conv3(b1, b2, b0, y3 + 1);
        loadrow(y0 + y3 + 3, b1); conv3(b2, b0, b1, y3 + 2);
    }
    loadrow(y0 + 16, b2); conv3(b0, b1, b2, 15);

    __shared__ float r1[256], r2[256];
    if (ch < 256) {
        r1[tid] = s1; r2[tid] = s2;
        __syncthreads();
        for (int st = 128; st > 0; st >>= 1) {
            if (tid < st) { r1[tid] += r1[tid + st]; r2[tid] += r2[tid + st]; }
            __syncthreads();
        }
        if (tid == 0) {
            if (ch < 128) { sumq[b * 128 + ch] = r1[0]; ssq[b * 128 + ch] = r2[0]; }
            else          { sumk[b * 128 + ch - 128] = r1[0]; ssk[b * 128 + ch - 128] = r2[0]; }
        }
    }
}

// combine: channel means (double) -> stable rank; rq,rk; gm
__global__ void combine_k(const float* __restrict__ sumq, const float* __restrict__ sumk,
    const float* __restrict__ ssq, const float* __restrict__ ssk,
    int* __restrict__ idxp, float* __restrict__ rqc, float* __restrict__ rkc,
    float* __restrict__ gm)
{
    const int t = threadIdx.x; // 128
    __shared__ double cms[128];
    double s = 0.0;
    for (int b = 0; b < B_; b++) s += (double)sumq[b * 128 + t];
    cms[t] = s;
    float rqv[B_], rkv[B_];
    for (int b = 0; b < B_; b++) {
        rqv[b] = 1.f / fmaxf(sqrtf(ssq[b * 128 + t]), 1e-12f);
        rkv[b] = 1.f / fmaxf(sqrtf(ssk[b * 128 + t]), 1e-12f);
        rqc[b * 128 + t] = rqv[b];
        rkc[b * 128 + t] = rkv[b];
    }
    __syncthreads();
    const double mv = cms[t];
    int r = 0;
    for (int j = 0; j < 128; j++) {
        double o = cms[j];
        if (o > mv || (o == mv && j < t)) r++;
    }
    idxp[r] = t;
    for (int b = 0; b < B_; b++)
        gm[b * 128 + r] = (rqv[b] * sumq[b * 128 + t] + rkv[b] * sumk[b * 128 + t]) * (1.0f / L_);
}

// ---------------------------------------------------------------------------
// Partial raw scores: S[c][d] = sum_l q[c,l]*k[d,l] over one L-split (per-G)
// ---------------------------------------------------------------------------
template<int G>
__global__ __launch_bounds__(256) void score_k(const float* __restrict__ dw, const int* __restrict__ idxp,
    int start, int gi, float* __restrict__ spart)
{
    constexpr int TS = G / 16;
    const int split = blockIdx.x, b = blockIdx.y;
    const int tid = threadIdx.x, tx = tid & 15, ty = tid >> 4;
    __shared__ float sQ[G][66];
    __shared__ float sK[G][66];
    __shared__ int sc[G];
    if (tid < G) sc[tid] = idxp[start + tid];
    __syncthreads();

    float acc[TS][TS];
#pragma unroll
    for (int i = 0; i < TS; i++)
#pragma unroll
        for (int j = 0; j < TS; j++) acc[i][j] = 0.f;

    const int l0 = split * (L_ / NS_);
    constexpr int LPT = (G * 64) / 256;
    for (int chk = 0; chk < L_ / NS_; chk += 64) {
#pragma unroll
        for (int i = 0; i < LPT; i++) {
            int id = tid + i * 256;
            int row = id >> 6, lc = id & 63;
            size_t base = ((size_t)b * O3_ + sc[row]) * L_ + l0 + chk + lc;
            sQ[row][lc] = dw[base];
            sK[row][lc] = dw[base + (size_t)128 * L_];
        }
        __syncthreads();
#pragma unroll
        for (int kk = 0; kk < 64; kk++) {
            float qv[TS], kv[TS];
#pragma unroll
            for (int j = 0; j < TS; j++) { qv[j] = sQ[ty * TS + j][kk]; kv[j] = sK[tx * TS + j][kk]; }
#pragma unroll
            for (int i = 0; i < TS; i++)
#pragma unroll
                for (int j = 0; j < TS; j++)
                    acc[i][j] = fmaf(qv[i], kv[j], acc[i][j]);
        }
        __syncthreads();
    }
    float* op = spart + (((size_t)(b * 4 + gi)) * NS_ + split) * MAXP_;
#pragma unroll
    for (int i = 0; i < TS; i++)
#pragma unroll
        for (int j = 0; j < TS; j++)
            op[(ty * TS + i) * G + tx * TS + j] = acc[i][j];
}

// reduce partials, scale by rq*rk*temp, softmax rows -> attn
__global__ __launch_bounds__(256) void softmax_k(const float* __restrict__ spart,
    const float* __restrict__ rqc, const float* __restrict__ rkc, const int* __restrict__ idxp,
    const float* __restrict__ temp, float* __restrict__ attn)
{
    const int gi = blockIdx.x, b = blockIdx.y;
    const int g = (gi == 0) ? 16 : (gi == 3 ? 48 : 32);
    const int start = (gi == 0) ? 0 : (gi == 1 ? 16 : (gi == 2 ? 48 : 80));
    __shared__ float S[MAXP_];
    __shared__ int sidx[48];
    if (threadIdx.x < g) sidx[threadIdx.x] = idxp[start + threadIdx.x];
    __syncthreads();
    const float tv = temp[gi];
    for (int p = threadIdx.x; p < g * g; p += 256) {
        float s = 0.f;
        const float* sp = spart + ((size_t)(b * 4 + gi)) * NS_ * MAXP_ + p;
        for (int k = 0; k < NS_; k++) s += sp[(size_t)k * MAXP_];
        int cc = p / g, dd = p - cc * g;
        S[p] = s * rqc[b * 128 + sidx[cc]] * rkc[b * 128 + sidx[dd]] * tv;
    }
    __syncthreads();
    const int wv = threadIdx.x >> 6, lane = threadIdx.x & 63;
    for (int r = wv; r < g; r += 4) {
        float val = (lane < g) ? S[r * g + lane] : -1e30f;
        float mx = val;
        for (int m = 32; m > 0; m >>= 1) mx = fmaxf(mx, __shfl_xor(mx, m));
        float e = (lane < g) ? expf(val - mx) : 0.f;
        float sum = e;
        for (int m = 32; m > 0; m >>= 1) sum += __shfl_xor(sum, m);
        if (lane < g) attn[((size_t)(b * 4 + gi)) * MAXP_ + r * g + lane] = e / sum;
    }
}

// ---------------------------------------------------------------------------
// attn @ v per-G: outallT fp32 [b][l][c]; sxy split hi/lo planes.
// LDS: sA + sV only (q,k read direct in epilogue).
// ---------------------------------------------------------------------------
template<int G>
__global__ __launch_bounds__(256) void av3_k(const float* __restrict__ dw, const int* __restrict__ idxp,
    const float* __restrict__ rqc, const float* __restrict__ rkc,
    const float* __restrict__ attn, int start, int gi,
    float* __restrict__ outallT, short* __restrict__ sxyhi, short* __restrict__ sxylo)
{
    constexpr int C4 = G / 4;
    constexpr int GP = G + 1;
    const int b = blockIdx.y;
    const int lB = blockIdx.x * 64;
    const int tid = threadIdx.x;
    __shared__ float sA[G * GP];
    __shared__ float sV[64][GP];
    __shared__ int cv[G];
    __shared__ float rqs[G], rks[G];
    if (tid < G) {
        int c0 = idxp[start + tid];
        cv[tid] = c0;
        rqs[tid] = rqc[b * 128 + c0];
        rks[tid] = rkc[b * 128 + c0];
    }
    for (int p = tid; p < G * G; p += 256) {
        int cc = p / G, dd = p - cc * G;
        sA[cc * GP + dd] = attn[((size_t)(b * 4 + gi)) * MAXP_ + p];
    }
    __syncthreads();
    for (int idx = tid; idx < 64 * G; idx += 256) {
        int l = idx & 63, d = idx >> 6;
        sV[l][d] = dw[((size_t)b * O3_ + 256 + cv[d]) * L_ + lB + l];
    }
    __syncthreads();
    const int strip = tid & 3, l = tid >> 2;
    float acc[C4];
#pragma unroll
    for (int j = 0; j < C4; j++) acc[j] = 0.f;
    for (int d = 0; d < G; d++) {
        float vd = sV[l][d];
#pragma unroll
        for (int j = 0; j < C4; j++)
            acc[j] = fmaf(sA[(strip * C4 + j) * GP + d], vd, acc[j]);
    }
    const size_t ob = ((size_t)b * L_ + lB + l) * C_ + start + strip * C4;
    float sv[C4];
#pragma unroll
    for (int j = 0; j < C4; j++) {
        int c = strip * C4 + j;
        float q = dw[((size_t)b * O3_ + cv[c]) * L_ + lB + l];
        float k = dw[((size_t)b * O3_ + 128 + cv[c]) * L_ + lB + l];
        sv[j] = acc[j] + rqs[c] * q + rks[c] * k;
    }
#pragma unroll
    for (int j = 0; j < C4; j += 4) {
        float4 o4 = {acc[j], acc[j + 1], acc[j + 2], acc[j + 3]};
        *reinterpret_cast<float4*>(&outallT[ob + j]) = o4;
    }
#pragma unroll
    for (int j = 0; j < C4; j += 2) {
        ushort h0 = f2bf(sv[j]), h1 = f2bf(sv[j + 1]);
        ushort g0 = f2bf(sv[j] - bf2f(h0)), g1 = f2bf(sv[j + 1] - bf2f(h1));
        *reinterpret_cast<uint*>(&sxyhi[ob + j]) = (uint)h0 | ((uint)h1 << 16);
        *reinterpret_cast<uint*>(&sxylo[ob + j]) = (uint)g0 | ((uint)g1 << 16);
    }
}

// qv_cache = 0.9 * mean of tiled group means, broadcast over spatial
__global__ __launch_bounds__(256) void qvc_k(const float* __restrict__ gm, float* __restrict__ outq)
{
    const int cpos = blockIdx.x, b = blockIdx.y;
    const float* g = gm + b * 128;
    float v = g[cpos & 15] + g[16 + (cpos & 31)] + g[48 + (cpos & 31)];
    if (cpos < 96) v += g[80 + (cpos % 48)];
    v *= 0.225f; // 0.9 * (sum/4)
    float4 vv = {v, v, v, v};
    float4* op = reinterpret_cast<float4*>(outq + ((size_t)b * C_ + cpos) * L_);
    for (int i = threadIdx.x; i < L_ / 4; i += 256) op[i] = vv;
}

// ---------------------------------------------------------------------------
extern "C" void kernel_launch(void* const* d_in, const int* in_sizes, int n_in,
                              void* d_out, int out_size, void* d_ws, size_t ws_size,
                              hipStream_t stream)
{
    const float* x     = (const float*)d_in[0];
    const float* temp  = (const float*)d_in[1];
    const float* wqkv  = (const float*)d_in[2];
    const float* wdw   = (const float*)d_in[3];
    const float* wproj = (const float*)d_in[4];
    const float* wgate = (const float*)d_in[5];
    const float* bgate = (const float*)d_in[6];
    const float* wdown = (const float*)d_in[7];
    const float* bdown = (const float*)d_in[8];
    const float* wup   = (const float*)d_in[9];
    const float* bup   = (const float*)d_in[10];
    float* out = (float*)d_out;
    float* ws  = (float*)d_ws;

    // --- ws layout ---
    float* qkvCL = ws;                          // [b][384][L] fp32  [0, 50331648)
    float* dwCL  = ws + 50331648ull;            // [b][384][L] fp32  [50331648, 100663296)
    short* xThi  = (short*)(ws + 50331648ull);  // xT planes: dead before dwconv writes
    short* xTlo  = xThi + 16777216ull;
    float* outallT = ws;                        // fp32 [b][L][128]   [0, 16777216)
    short* sxyhi   = (short*)(ws + 16777216ull);
    short* sxylo   = sxyhi + 16777216ull;
    short* gatedhi = (short*)(ws + 33554432ull);
    short* gatedlo = gatedhi + 16777216ull;
    short* mod1hi  = (short*)(ws + 16777216ull);
    short* mod1lo  = mod1hi + 8388608ull;
    short* out2hi  = (short*)(ws + 33554432ull);
    short* out2lo  = out2hi + 16777216ull;

    // --- d_out layout (first half scratch until proj; second half qv_cache) ---
    float* spart = out;                         // [0, 4718592)
    float* attn  = out + 4718592ull;
    float* sumq  = out + 4800000ull;
    float* sumk  = out + 4801024ull;
    float* ssq   = out + 4802048ull;
    float* ssk   = out + 4803072ull;
    float* rqc   = out + 4804096ull;
    float* rkc   = out + 4805120ull;
    float* gm    = out + 4806144ull;
    int*   idxp  = (int*)(out + 4807168ull);

    // 1. transpose+split x
    transp_k<<<dim3(512, 8), 256, 0, stream>>>(x, xThi, xTlo);
    // 2. qkv GEMM -> qkvCL fp32 [b][384][l]
    mgemm_k<128, 128, 4><<<dim3(3, 128, 8), 256, 0, stream>>>(
        wqkv, nullptr, xThi, xTlo, nullptr, qkvCL, nullptr, nullptr);
    // 3. depthwise 3x3 + fused q/k sums
    dwconv_k<<<dim3(384, 8), 256, 0, stream>>>(qkvCL, wdw, dwCL, sumq, sumk, ssq, ssk);
    // 4. combine: rank + norms + gm
    combine_k<<<1, 128, 0, stream>>>(sumq, sumk, ssq, ssk, idxp, rqc, rkc, gm);
    // 5. attention scores (per-G launches)
    score_k<16><<<dim3(NS_, 8), 256, 0, stream>>>(dwCL, idxp, 0, 0, spart);
    score_k<32><<<dim3(NS_, 8), 256, 0, stream>>>(dwCL, idxp, 16, 1, spart);
    score_k<32><<<dim3(NS_, 8), 256, 0, stream>>>(dwCL, idxp, 48, 2, spart);
    score_k<48><<<dim3(NS_, 8), 256, 0, stream>>>(dwCL, idxp, 80, 3, spart);
    // 6. reduce + softmax
    softmax_k<<<dim3(4, 8), 256, 0, stream>>>(spart, rqc, rkc, idxp, temp, attn);
    // 7. attn @ v (per-G launches) -> outallT fp32 + sxy hi/lo planes
    av3_k<16><<<dim3(256, 8), 256, 0, stream>>>(dwCL, idxp, rqc, rkc, attn, 0, 0, outallT, sxyhi, sxylo);
    av3_k<32><<<dim3(256, 8), 256, 0, stream>>>(dwCL, idxp, rqc, rkc, attn, 16, 1, outallT, sxyhi, sxylo);
    av3_k<32><<<dim3(256, 8), 256, 0, stream>>>(dwCL, idxp, rqc, rkc, attn, 48, 2, outallT, sxyhi, sxylo);
    av3_k<48><<<dim3(256, 8), 256, 0, stream>>>(dwCL, idxp, rqc, rkc, attn, 80, 3, outallT, sxyhi, sxylo);
    // 8. gate GEMM (+gelu * sxy)
    mgemm_k<128, 128, 1><<<dim3(1, 128, 8), 256, 0, stream>>>(
        wgate, bgate, sxyhi, sxylo, nullptr, nullptr, gatedhi, gatedlo);
    // 9. qv_cache
    qvc_k<<<dim3(128, 8), 256, 0, stream>>>(gm, out + 16777216ull);
    // 10. down GEMM
    mgemm_k<128, 64, 2><<<dim3(1, 128, 8), 256, 0, stream>>>(
        wdown, bdown, gatedhi, gatedlo, nullptr, nullptr, mod1hi, mod1lo);
    // 11. up GEMM + residual
    mgemm_k<64, 128, 3><<<dim3(1, 128, 8), 256, 0, stream>>>(
        wup, bup, mod1hi, mod1lo, outallT, nullptr, out2hi, out2lo);
    // 12. proj GEMM -> final output fp32 [b][128][l]
    mgemm_k<128, 128, 4><<<dim3(1, 128, 8), 256, 0, stream>>>(
        wproj, nullptr, out2hi, out2lo, nullptr, out, nullptr, nullptr);
}

// Round 6
// 729.621 us; speedup vs baseline: 1.1356x; 1.1355x over previous
//
#include <hip/hip_runtime.h>
#include <math.h>

#define B_ 8
#define C_ 128
#define O3_ 384
#define H_ 128
#define W_ 128
#define L_ 16384
#define NS_ 64
#define MAXP_ 2304

typedef float f32x4 __attribute__((ext_vector_type(4)));
typedef short bf16x8 __attribute__((ext_vector_type(8)));

static __device__ __forceinline__ ushort f2bf(float f) {
    uint u = __float_as_uint(f);
    u += 0x7fffu + ((u >> 16) & 1u);
    return (ushort)(u >> 16);
}
static __device__ __forceinline__ float bf2f(ushort h) {
    return __uint_as_float(((uint)h) << 16);
}

// ---------------------------------------------------------------------------
// Weight pre-split: fp32 -> hi/lo bf16 planes (4 weights in one launch)
// ---------------------------------------------------------------------------
__global__ __launch_bounds__(256) void wsplit_k(
    const float* __restrict__ wa, const float* __restrict__ wb,
    const float* __restrict__ wc, const float* __restrict__ wd,
    short* __restrict__ ha, short* __restrict__ la,
    short* __restrict__ hb, short* __restrict__ lb,
    short* __restrict__ hc, short* __restrict__ lc,
    short* __restrict__ hd, short* __restrict__ ld)
{
    const int sel = blockIdx.y;
    const float* w = sel == 0 ? wa : (sel == 1 ? wb : (sel == 2 ? wc : wd));
    short* ph = sel == 0 ? ha : (sel == 1 ? hb : (sel == 2 ? hc : hd));
    short* pl = sel == 0 ? la : (sel == 1 ? lb : (sel == 2 ? lc : ld));
    const int n = sel == 0 ? 49152 : (sel == 1 ? 16384 : 8192);
    const int i = blockIdx.x * 256 + threadIdx.x;
    if (i < n) {
        float v = w[i];
        ushort h = f2bf(v);
        ph[i] = (short)h;
        pl[i] = (short)f2bf(v - bf2f(h));
    }
}

__global__ __launch_bounds__(256) void wsplit1_k(const float* __restrict__ w,
    short* __restrict__ ph, short* __restrict__ pl, int n)
{
    const int i = blockIdx.x * 256 + threadIdx.x;
    if (i < n) {
        float v = w[i];
        ushort h = f2bf(v);
        ph[i] = (short)h;
        pl[i] = (short)f2bf(v - bf2f(h));
    }
}

// ---------------------------------------------------------------------------
// Transpose+split: x [b][128c][L] fp32 -> xThi/xTlo [b][L][128c] bf16 planes
// ---------------------------------------------------------------------------
__global__ __launch_bounds__(256) void transp_k(const float* __restrict__ x,
    short* __restrict__ xhi, short* __restrict__ xlo)
{
    __shared__ float t[128][33];
    const int b = blockIdx.y;
    const int l0 = blockIdx.x * 32;
    const int tid = threadIdx.x;
    {
        const int c = tid >> 1, half = tid & 1;
        const float* src = x + ((size_t)b * C_ + c) * L_ + l0 + half * 16;
#pragma unroll
        for (int u = 0; u < 4; u++) {
            float4 v = *reinterpret_cast<const float4*>(src + u * 4);
            t[c][half * 16 + u * 4 + 0] = v.x;
            t[c][half * 16 + u * 4 + 1] = v.y;
            t[c][half * 16 + u * 4 + 2] = v.z;
            t[c][half * 16 + u * 4 + 3] = v.w;
        }
    }
    __syncthreads();
    {
        const int l = tid >> 3, strip = tid & 7;
        uint hi[8], lo[8];
#pragma unroll
        for (int i = 0; i < 8; i++) {
            float a0 = t[strip * 16 + 2 * i][l], a1 = t[strip * 16 + 2 * i + 1][l];
            ushort h0 = f2bf(a0), h1 = f2bf(a1);
            ushort g0 = f2bf(a0 - bf2f(h0)), g1 = f2bf(a1 - bf2f(h1));
            hi[i] = (uint)h0 | ((uint)h1 << 16);
            lo[i] = (uint)g0 | ((uint)g1 << 16);
        }
        size_t ob = ((size_t)b * L_ + l0 + l) * C_ + strip * 16;
        uint4* ph = reinterpret_cast<uint4*>(xhi + ob);
        uint4* pl = reinterpret_cast<uint4*>(xlo + ob);
        ph[0] = *reinterpret_cast<uint4*>(&hi[0]);
        ph[1] = *reinterpret_cast<uint4*>(&hi[4]);
        pl[0] = *reinterpret_cast<uint4*>(&lo[0]);
        pl[1] = *reinterpret_cast<uint4*>(&lo[4]);
    }
}

// ---------------------------------------------------------------------------
// NT MFMA GEMM (bf16x3), register-prefetch pipeline, pre-split A and W planes.
// MODE 1: y = gelu(acc+bias) * (A-reconstruct at yi)  -> split store [l][o]
// MODE 2: y = acc+bias                                 -> split store [l][o]
// MODE 3: y = acc+bias+E0                              -> split store [l][o]
// MODE 4: plain, fp32 transposed store [o][l]
// ---------------------------------------------------------------------------
template<int KD, int OT, int MODE>
__global__ __launch_bounds__(256) void mgemm_k(
    const short* __restrict__ Whi, const short* __restrict__ Wlo,
    const float* __restrict__ bias,
    const short* __restrict__ Ahi, const short* __restrict__ Alo,
    const float* __restrict__ E0,
    float* __restrict__ Yf, short* __restrict__ Yhi, short* __restrict__ Ylo)
{
    constexpr int NR = OT / 32;
    constexpr int T = KD / 32;
    constexpr int BPT = (OT * 4) / 256;   // B chunks/thread: 2 (OT=128) or 1 (OT=64)
    __shared__ short sAh[128][40];
    __shared__ short sAl[128][40];
    __shared__ short sBh[OT][40];
    __shared__ short sBl[OT][40];
    const int tid = threadIdx.x;
    const int lane = tid & 63;
    const int wid = tid >> 6;
    const int wr = wid >> 1, wc = wid & 1;
    const int oB = blockIdx.x * OT;
    const int lB = blockIdx.y * 128;
    const int ON = gridDim.x * OT;
    const int b = blockIdx.z;
    const int ln15 = lane & 15, lg = lane >> 4;

    const int al0 = tid >> 2, ac8 = (tid & 3) * 8;
    const size_t abase = ((size_t)b * L_ + lB + al0) * KD + ac8;

    f32x4 acc[4][NR];
#pragma unroll
    for (int m = 0; m < 4; m++)
#pragma unroll
        for (int n = 0; n < NR; n++)
#pragma unroll
            for (int r = 0; r < 4; r++) acc[m][n][r] = 0.f;

    bf16x8 pAh[2], pAl[2], pBh[BPT], pBl[BPT];

    auto ldA = [&](int t) {
#pragma unroll
        for (int p = 0; p < 2; p++) {
            size_t g = abase + (size_t)p * 64 * KD + t * 32;
            pAh[p] = *reinterpret_cast<const bf16x8*>(Ahi + g);
            pAl[p] = *reinterpret_cast<const bf16x8*>(Alo + g);
        }
    };
    auto ldB = [&](int t) {
#pragma unroll
        for (int p = 0; p < BPT; p++) {
            int idx = tid + p * 256;
            int o = idx >> 2, c8 = (idx & 3) * 8;
            size_t g = (size_t)(oB + o) * KD + t * 32 + c8;
            pBh[p] = *reinterpret_cast<const bf16x8*>(Whi + g);
            pBl[p] = *reinterpret_cast<const bf16x8*>(Wlo + g);
        }
    };
    auto stAB = [&]() {
#pragma unroll
        for (int p = 0; p < 2; p++) {
            *reinterpret_cast<bf16x8*>(&sAh[al0 + p * 64][ac8]) = pAh[p];
            *reinterpret_cast<bf16x8*>(&sAl[al0 + p * 64][ac8]) = pAl[p];
        }
#pragma unroll
        for (int p = 0; p < BPT; p++) {
            int idx = tid + p * 256;
            int o = idx >> 2, c8 = (idx & 3) * 8;
            *reinterpret_cast<bf16x8*>(&sBh[o][c8]) = pBh[p];
            *reinterpret_cast<bf16x8*>(&sBl[o][c8]) = pBl[p];
        }
    };

    ldA(0); ldB(0);
    stAB();
    __syncthreads();

    for (int t = 0; t < T; t++) {
        if (t + 1 < T) { ldA(t + 1); ldB(t + 1); }   // issue next-tile loads early
        bf16x8 Ah[4], Al[4];
#pragma unroll
        for (int m = 0; m < 4; m++) {
            int row = wr * 64 + m * 16 + ln15;
            Ah[m] = *reinterpret_cast<const bf16x8*>(&sAh[row][lg * 8]);
            Al[m] = *reinterpret_cast<const bf16x8*>(&sAl[row][lg * 8]);
        }
#pragma unroll
        for (int n = 0; n < NR; n++) {
            int brow = wc * (OT / 2) + n * 16 + ln15;
            bf16x8 Bh = *reinterpret_cast<const bf16x8*>(&sBh[brow][lg * 8]);
            bf16x8 Bl = *reinterpret_cast<const bf16x8*>(&sBl[brow][lg * 8]);
#pragma unroll
            for (int m = 0; m < 4; m++) {
                acc[m][n] = __builtin_amdgcn_mfma_f32_16x16x32_bf16(Ah[m], Bh, acc[m][n], 0, 0, 0);
                acc[m][n] = __builtin_amdgcn_mfma_f32_16x16x32_bf16(Ah[m], Bl, acc[m][n], 0, 0, 0);
                acc[m][n] = __builtin_amdgcn_mfma_f32_16x16x32_bf16(Al[m], Bh, acc[m][n], 0, 0, 0);
            }
        }
        __syncthreads();
        if (t + 1 < T) { stAB(); __syncthreads(); }
    }

#pragma unroll
    for (int m = 0; m < 4; m++) {
        const int lg4 = lB + wr * 64 + m * 16 + lg * 4;
#pragma unroll
        for (int n = 0; n < NR; n++) {
            const int o = oB + wc * (OT / 2) + n * 16 + ln15;
            if constexpr (MODE == 4) {
                float4 r4 = {acc[m][n][0], acc[m][n][1], acc[m][n][2], acc[m][n][3]};
                *reinterpret_cast<float4*>(&Yf[((size_t)b * ON + o) * L_ + lg4]) = r4;
            } else {
                float bv = bias[o];
#pragma unroll
                for (int r = 0; r < 4; r++) {
                    size_t yi = ((size_t)b * L_ + lg4 + r) * ON + o;
                    float a = acc[m][n][r] + bv;
                    if constexpr (MODE == 1) {
                        float sxy = bf2f((ushort)Ahi[yi]) + bf2f((ushort)Alo[yi]);
                        a = 0.5f * a * (1.f + erff(a * 0.70710678118654752f)) * sxy;
                    }
                    if constexpr (MODE == 3) a += E0[yi];
                    ushort h = f2bf(a);
                    ushort g = f2bf(a - bf2f(h));
                    Yhi[yi] = (short)h;
                    Ylo[yi] = (short)g;
                }
            }
        }
    }
}

// ---------------------------------------------------------------------------
// Depthwise 3x3 SAME conv, register-rolling, fused q/k sum & sumsq reduction
// ---------------------------------------------------------------------------
__global__ __launch_bounds__(256) void dwconv_k(const float* __restrict__ in,
    const float* __restrict__ wdw, float* __restrict__ outp,
    float* __restrict__ sumq, float* __restrict__ sumk,
    float* __restrict__ ssq, float* __restrict__ ssk)
{
    const int ch = blockIdx.x, b = blockIdx.y;
    const int tid = threadIdx.x;
    const int tx = tid & 31, band = tid >> 5;
    const int x0 = tx * 4;
    const int y0 = band * 16;
    const size_t base = ((size_t)b * O3_ + ch) * L_;
    const float* wp = wdw + ch * 9;
    float w0 = wp[0], w1 = wp[1], w2 = wp[2], w3 = wp[3], w4 = wp[4],
          w5 = wp[5], w6 = wp[6], w7 = wp[7], w8 = wp[8];

    float s1 = 0.f, s2 = 0.f;
    float b0[6], b1[6], b2[6];

    auto loadrow = [&](int gy, float* r) {
        if ((unsigned)gy < (unsigned)H_) {
            const float* rp = in + base + (size_t)gy * W_;
            float4 m = *reinterpret_cast<const float4*>(rp + x0);
            r[0] = (x0 > 0) ? rp[x0 - 1] : 0.f;
            r[1] = m.x; r[2] = m.y; r[3] = m.z; r[4] = m.w;
            r[5] = (x0 < W_ - 4) ? rp[x0 + 4] : 0.f;
        } else {
            r[0] = r[1] = r[2] = r[3] = r[4] = r[5] = 0.f;
        }
    };
    auto conv3 = [&](const float* ra, const float* rb, const float* rc, int yy) {
        float o0 = ra[0]*w0 + ra[1]*w1 + ra[2]*w2 + rb[0]*w3 + rb[1]*w4 + rb[2]*w5 + rc[0]*w6 + rc[1]*w7 + rc[2]*w8;
        float o1 = ra[1]*w0 + ra[2]*w1 + ra[3]*w2 + rb[1]*w3 + rb[2]*w4 + rb[3]*w5 + rc[1]*w6 + rc[2]*w7 + rc[3]*w8;
        float o2 = ra[2]*w0 + ra[3]*w1 + ra[4]*w2 + rb[2]*w3 + rb[3]*w4 + rb[4]*w5 + rc[2]*w6 + rc[3]*w7 + rc[4]*w8;
        float o3 = ra[3]*w0 + ra[4]*w1 + ra[5]*w2 + rb[3]*w3 + rb[4]*w4 + rb[5]*w5 + rc[3]*w6 + rc[4]*w7 + rc[5]*w8;
        float4 o4 = {o0, o1, o2, o3};
        *reinterpret_cast<float4*>(&outp[base + (size_t)(y0 + yy) * W_ + x0]) = o4;
        s1 += (o0 + o1) + (o2 + o3);
        s2 += o0*o0 + o1*o1 + o2*o2 + o3*o3;
    };

    loadrow(y0 - 1, b0);
    loadrow(y0,     b1);
#pragma unroll
    for (int y3 = 0; y3 < 15; y3 += 3) {
        loadrow(y0 + y3 + 1, b2); conv3(b0, b1, b2, y3);
        loadrow(y0 + y3 + 2, b0); conv3(b1, b2, b0, y3 + 1);
        loadrow(y0 + y3 + 3, b1); conv3(b2, b0, b1, y3 + 2);
    }
    loadrow(y0 + 16, b2); conv3(b0, b1, b2, 15);

    __shared__ float r1[256], r2[256];
    if (ch < 256) {
        r1[tid] = s1; r2[tid] = s2;
        __syncthreads();
        for (int st = 128; st > 0; st >>= 1) {
            if (tid < st) { r1[tid] += r1[tid + st]; r2[tid] += r2[tid + st]; }
            __syncthreads();
        }
        if (tid == 0) {
            if (ch < 128) { sumq[b * 128 + ch] = r1[0]; ssq[b * 128 + ch] = r2[0]; }
            else          { sumk[b * 128 + ch - 128] = r1[0]; ssk[b * 128 + ch - 128] = r2[0]; }
        }
    }
}

// combine: channel means (double) -> stable rank; rq,rk; gm
__global__ void combine_k(const float* __restrict__ sumq, const float* __restrict__ sumk,
    const float* __restrict__ ssq, const float* __restrict__ ssk,
    int* __restrict__ idxp, float* __restrict__ rqc, float* __restrict__ rkc,
    float* __restrict__ gm)
{
    const int t = threadIdx.x; // 128
    __shared__ double cms[128];
    double s = 0.0;
    for (int b = 0; b < B_; b++) s += (double)sumq[b * 128 + t];
    cms[t] = s;
    float rqv[B_], rkv[B_];
    for (int b = 0; b < B_; b++) {
        rqv[b] = 1.f / fmaxf(sqrtf(ssq[b * 128 + t]), 1e-12f);
        rkv[b] = 1.f / fmaxf(sqrtf(ssk[b * 128 + t]), 1e-12f);
        rqc[b * 128 + t] = rqv[b];
        rkc[b * 128 + t] = rkv[b];
    }
    __syncthreads();
    const double mv = cms[t];
    int r = 0;
    for (int j = 0; j < 128; j++) {
        double o = cms[j];
        if (o > mv || (o == mv && j < t)) r++;
    }
    idxp[r] = t;
    for (int b = 0; b < B_; b++)
        gm[b * 128 + r] = (rqv[b] * sumq[b * 128 + t] + rkv[b] * sumk[b * 128 + t]) * (1.0f / L_);
}

// ---------------------------------------------------------------------------
// Partial raw scores: S[c][d] = sum_l q[c,l]*k[d,l] over one L-split (per-G)
// ---------------------------------------------------------------------------
template<int G>
__global__ __launch_bounds__(256) void score_k(const float* __restrict__ dw, const int* __restrict__ idxp,
    int start, int gi, float* __restrict__ spart)
{
    constexpr int TS = G / 16;
    const int split = blockIdx.x, b = blockIdx.y;
    const int tid = threadIdx.x, tx = tid & 15, ty = tid >> 4;
    __shared__ float sQ[G][66];
    __shared__ float sK[G][66];
    __shared__ int sc[G];
    if (tid < G) sc[tid] = idxp[start + tid];
    __syncthreads();

    float acc[TS][TS];
#pragma unroll
    for (int i = 0; i < TS; i++)
#pragma unroll
        for (int j = 0; j < TS; j++) acc[i][j] = 0.f;

    const int l0 = split * (L_ / NS_);
    constexpr int LPT = (G * 64) / 256;
    for (int chk = 0; chk < L_ / NS_; chk += 64) {
#pragma unroll
        for (int i = 0; i < LPT; i++) {
            int id = tid + i * 256;
            int row = id >> 6, lc = id & 63;
            size_t base = ((size_t)b * O3_ + sc[row]) * L_ + l0 + chk + lc;
            sQ[row][lc] = dw[base];
            sK[row][lc] = dw[base + (size_t)128 * L_];
        }
        __syncthreads();
#pragma unroll
        for (int kk = 0; kk < 64; kk++) {
            float qv[TS], kv[TS];
#pragma unroll
            for (int j = 0; j < TS; j++) { qv[j] = sQ[ty * TS + j][kk]; kv[j] = sK[tx * TS + j][kk]; }
#pragma unroll
            for (int i = 0; i < TS; i++)
#pragma unroll
                for (int j = 0; j < TS; j++)
                    acc[i][j] = fmaf(qv[i], kv[j], acc[i][j]);
        }
        __syncthreads();
    }
    float* op = spart + (((size_t)(b * 4 + gi)) * NS_ + split) * MAXP_;
#pragma unroll
    for (int i = 0; i < TS; i++)
#pragma unroll
        for (int j = 0; j < TS; j++)
            op[(ty * TS + i) * G + tx * TS + j] = acc[i][j];
}

// reduce partials, scale by rq*rk*temp, softmax rows -> attn
__global__ __launch_bounds__(256) void softmax_k(const float* __restrict__ spart,
    const float* __restrict__ rqc, const float* __restrict__ rkc, const int* __restrict__ idxp,
    const float* __restrict__ temp, float* __restrict__ attn)
{
    const int gi = blockIdx.x, b = blockIdx.y;
    const int g = (gi == 0) ? 16 : (gi == 3 ? 48 : 32);
    const int start = (gi == 0) ? 0 : (gi == 1 ? 16 : (gi == 2 ? 48 : 80));
    __shared__ float S[MAXP_];
    __shared__ int sidx[48];
    if (threadIdx.x < g) sidx[threadIdx.x] = idxp[start + threadIdx.x];
    __syncthreads();
    const float tv = temp[gi];
    for (int p = threadIdx.x; p < g * g; p += 256) {
        float s = 0.f;
        const float* sp = spart + ((size_t)(b * 4 + gi)) * NS_ * MAXP_ + p;
        for (int k = 0; k < NS_; k++) s += sp[(size_t)k * MAXP_];
        int cc = p / g, dd = p - cc * g;
        S[p] = s * rqc[b * 128 + sidx[cc]] * rkc[b * 128 + sidx[dd]] * tv;
    }
    __syncthreads();
    const int wv = threadIdx.x >> 6, lane = threadIdx.x & 63;
    for (int r = wv; r < g; r += 4) {
        float val = (lane < g) ? S[r * g + lane] : -1e30f;
        float mx = val;
        for (int m = 32; m > 0; m >>= 1) mx = fmaxf(mx, __shfl_xor(mx, m));
        float e = (lane < g) ? expf(val - mx) : 0.f;
        float sum = e;
        for (int m = 32; m > 0; m >>= 1) sum += __shfl_xor(sum, m);
        if (lane < g) attn[((size_t)(b * 4 + gi)) * MAXP_ + r * g + lane] = e / sum;
    }
}

// ---------------------------------------------------------------------------
// attn @ v per-G: outallT fp32 [b][l][c]; sxy split hi/lo planes.
// ---------------------------------------------------------------------------
template<int G>
__global__ __launch_bounds__(256) void av3_k(const float* __restrict__ dw, const int* __restrict__ idxp,
    const float* __restrict__ rqc, const float* __restrict__ rkc,
    const float* __restrict__ attn, int start, int gi,
    float* __restrict__ outallT, short* __restrict__ sxyhi, short* __restrict__ sxylo)
{
    constexpr int C4 = G / 4;
    constexpr int GP = G + 1;
    const int b = blockIdx.y;
    const int lB = blockIdx.x * 64;
    const int tid = threadIdx.x;
    __shared__ float sA[G * GP];
    __shared__ float sV[64][GP];
    __shared__ int cv[G];
    __shared__ float rqs[G], rks[G];
    if (tid < G) {
        int c0 = idxp[start + tid];
        cv[tid] = c0;
        rqs[tid] = rqc[b * 128 + c0];
        rks[tid] = rkc[b * 128 + c0];
    }
    for (int p = tid; p < G * G; p += 256) {
        int cc = p / G, dd = p - cc * G;
        sA[cc * GP + dd] = attn[((size_t)(b * 4 + gi)) * MAXP_ + p];
    }
    __syncthreads();
    for (int idx = tid; idx < 64 * G; idx += 256) {
        int l = idx & 63, d = idx >> 6;
        sV[l][d] = dw[((size_t)b * O3_ + 256 + cv[d]) * L_ + lB + l];
    }
    __syncthreads();
    const int strip = tid & 3, l = tid >> 2;
    float acc[C4];
#pragma unroll
    for (int j = 0; j < C4; j++) acc[j] = 0.f;
    for (int d = 0; d < G; d++) {
        float vd = sV[l][d];
#pragma unroll
        for (int j = 0; j < C4; j++)
            acc[j] = fmaf(sA[(strip * C4 + j) * GP + d], vd, acc[j]);
    }
    const size_t ob = ((size_t)b * L_ + lB + l) * C_ + start + strip * C4;
    float sv[C4];
#pragma unroll
    for (int j = 0; j < C4; j++) {
        int c = strip * C4 + j;
        float q = dw[((size_t)b * O3_ + cv[c]) * L_ + lB + l];
        float k = dw[((size_t)b * O3_ + 128 + cv[c]) * L_ + lB + l];
        sv[j] = acc[j] + rqs[c] * q + rks[c] * k;
    }
#pragma unroll
    for (int j = 0; j < C4; j += 4) {
        float4 o4 = {acc[j], acc[j + 1], acc[j + 2], acc[j + 3]};
        *reinterpret_cast<float4*>(&outallT[ob + j]) = o4;
    }
#pragma unroll
    for (int j = 0; j < C4; j += 2) {
        ushort h0 = f2bf(sv[j]), h1 = f2bf(sv[j + 1]);
        ushort g0 = f2bf(sv[j] - bf2f(h0)), g1 = f2bf(sv[j + 1] - bf2f(h1));
        *reinterpret_cast<uint*>(&sxyhi[ob + j]) = (uint)h0 | ((uint)h1 << 16);
        *reinterpret_cast<uint*>(&sxylo[ob + j]) = (uint)g0 | ((uint)g1 << 16);
    }
}

// qv_cache = 0.9 * mean of tiled group means, broadcast over spatial
__global__ __launch_bounds__(256) void qvc_k(const float* __restrict__ gm, float* __restrict__ outq)
{
    const int cpos = blockIdx.x, b = blockIdx.y;
    const float* g = gm + b * 128;
    float v = g[cpos & 15] + g[16 + (cpos & 31)] + g[48 + (cpos & 31)];
    if (cpos < 96) v += g[80 + (cpos % 48)];
    v *= 0.225f; // 0.9 * (sum/4)
    float4 vv = {v, v, v, v};
    float4* op = reinterpret_cast<float4*>(outq + ((size_t)b * C_ + cpos) * L_);
    for (int i = threadIdx.x; i < L_ / 4; i += 256) op[i] = vv;
}

// ---------------------------------------------------------------------------
extern "C" void kernel_launch(void* const* d_in, const int* in_sizes, int n_in,
                              void* d_out, int out_size, void* d_ws, size_t ws_size,
                              hipStream_t stream)
{
    const float* x     = (const float*)d_in[0];
    const float* temp  = (const float*)d_in[1];
    const float* wqkv  = (const float*)d_in[2];
    const float* wdw   = (const float*)d_in[3];
    const float* wproj = (const float*)d_in[4];
    const float* wgate = (const float*)d_in[5];
    const float* bgate = (const float*)d_in[6];
    const float* wdown = (const float*)d_in[7];
    const float* bdown = (const float*)d_in[8];
    const float* wup   = (const float*)d_in[9];
    const float* bup   = (const float*)d_in[10];
    float* out = (float*)d_out;
    float* ws  = (float*)d_ws;

    // --- ws layout ---
    float* qkvCL = ws;                          // [b][384][L] fp32  [0, 50331648)
    float* dwCL  = ws + 50331648ull;            // [b][384][L] fp32  [50331648, 100663296)
    short* xThi  = (short*)(ws + 50331648ull);  // xT planes: dead before dwconv writes
    short* xTlo  = xThi + 16777216ull;
    float* outallT = ws;                        // fp32 [b][L][128]   [0, 16777216)
    short* sxyhi   = (short*)(ws + 16777216ull);
    short* sxylo   = sxyhi + 16777216ull;
    short* gatedhi = (short*)(ws + 33554432ull);
    short* gatedlo = gatedhi + 16777216ull;
    short* mod1hi  = (short*)(ws + 16777216ull);
    short* mod1lo  = mod1hi + 8388608ull;
    short* out2hi  = (short*)(ws + 33554432ull);
    short* out2lo  = out2hi + 16777216ull;
    // wproj planes: created after up, in the then-dead mod1 region tail
    short* wprojh  = (short*)(ws + 25165824ull);
    short* wprojl  = wprojh + 16384ull;

    // --- d_out layout (first half scratch until proj; second half qv_cache) ---
    float* spart = out;                         // [0, 4718592)
    float* attn  = out + 4718592ull;
    float* sumq  = out + 4800000ull;
    float* sumk  = out + 4801024ull;
    float* ssq   = out + 4802048ull;
    float* ssk   = out + 4803072ull;
    float* rqc   = out + 4804096ull;
    float* rkc   = out + 4805120ull;
    float* gm    = out + 4806144ull;
    int*   idxp  = (int*)(out + 4807168ull);
    // weight hi/lo planes (dead region until proj overwrites; consumed before)
    short* wqkvh = (short*)(out + 4900000ull);  // 49152 shorts
    short* wqkvl = (short*)(out + 4924576ull);
    short* wgateh= (short*)(out + 4949152ull);  // 16384 shorts
    short* wgatel= (short*)(out + 4957344ull);
    short* wdownh= (short*)(out + 4965536ull);  // 8192 shorts
    short* wdownl= (short*)(out + 4969632ull);
    short* wuph  = (short*)(out + 4973728ull);  // 8192 shorts
    short* wupl  = (short*)(out + 4977824ull);

    // 0. weight pre-split (qkv, gate, down, up)
    wsplit_k<<<dim3(192, 4), 256, 0, stream>>>(wqkv, wgate, wdown, wup,
        wqkvh, wqkvl, wgateh, wgatel, wdownh, wdownl, wuph, wupl);
    // 1. transpose+split x
    transp_k<<<dim3(512, 8), 256, 0, stream>>>(x, xThi, xTlo);
    // 2. qkv GEMM -> qkvCL fp32 [b][384][l]
    mgemm_k<128, 128, 4><<<dim3(3, 128, 8), 256, 0, stream>>>(
        wqkvh, wqkvl, nullptr, xThi, xTlo, nullptr, qkvCL, nullptr, nullptr);
    // 3. depthwise 3x3 + fused q/k sums
    dwconv_k<<<dim3(384, 8), 256, 0, stream>>>(qkvCL, wdw, dwCL, sumq, sumk, ssq, ssk);
    // 4. combine: rank + norms + gm
    combine_k<<<1, 128, 0, stream>>>(sumq, sumk, ssq, ssk, idxp, rqc, rkc, gm);
    // 5. attention scores (per-G launches)
    score_k<16><<<dim3(NS_, 8), 256, 0, stream>>>(dwCL, idxp, 0, 0, spart);
    score_k<32><<<dim3(NS_, 8), 256, 0, stream>>>(dwCL, idxp, 16, 1, spart);
    score_k<32><<<dim3(NS_, 8), 256, 0, stream>>>(dwCL, idxp, 48, 2, spart);
    score_k<48><<<dim3(NS_, 8), 256, 0, stream>>>(dwCL, idxp, 80, 3, spart);
    // 6. reduce + softmax
    softmax_k<<<dim3(4, 8), 256, 0, stream>>>(spart, rqc, rkc, idxp, temp, attn);
    // 7. attn @ v (per-G launches) -> outallT fp32 + sxy hi/lo planes
    av3_k<16><<<dim3(256, 8), 256, 0, stream>>>(dwCL, idxp, rqc, rkc, attn, 0, 0, outallT, sxyhi, sxylo);
    av3_k<32><<<dim3(256, 8), 256, 0, stream>>>(dwCL, idxp, rqc, rkc, attn, 16, 1, outallT, sxyhi, sxylo);
    av3_k<32><<<dim3(256, 8), 256, 0, stream>>>(dwCL, idxp, rqc, rkc, attn, 48, 2, outallT, sxyhi, sxylo);
    av3_k<48><<<dim3(256, 8), 256, 0, stream>>>(dwCL, idxp, rqc, rkc, attn, 80, 3, outallT, sxyhi, sxylo);
    // 8. gate GEMM (+gelu * sxy)
    mgemm_k<128, 128, 1><<<dim3(1, 128, 8), 256, 0, stream>>>(
        wgateh, wgatel, bgate, sxyhi, sxylo, nullptr, nullptr, gatedhi, gatedlo);
    // 9. qv_cache
    qvc_k<<<dim3(128, 8), 256, 0, stream>>>(gm, out + 16777216ull);
    // 10. down GEMM
    mgemm_k<128, 64, 2><<<dim3(1, 128, 8), 256, 0, stream>>>(
        wdownh, wdownl, bdown, gatedhi, gatedlo, nullptr, nullptr, mod1hi, mod1lo);
    // 11. up GEMM + residual
    mgemm_k<64, 128, 3><<<dim3(1, 128, 8), 256, 0, stream>>>(
        wuph, wupl, bup, mod1hi, mod1lo, outallT, nullptr, out2hi, out2lo);
    // 12. wproj pre-split (mod1 region is dead now)
    wsplit1_k<<<64, 256, 0, stream>>>(wproj, wprojh, wprojl, 16384);
    // 13. proj GEMM -> final output fp32 [b][128][l]
    mgemm_k<128, 128, 4><<<dim3(1, 128, 8), 256, 0, stream>>>(
        wprojh, wprojl, nullptr, out2hi, out2lo, nullptr, out, nullptr, nullptr);
}